// Round 11
// baseline (2868.970 us; speedup 1.0000x reference)
//
#include <hip/hip_runtime.h>
#include <hip/hip_bf16.h>
#include <stdint.h>

// Problem constants
#define NB_B 2048
#define NN   64
#define DD   256
#define HH   1024
#define EE   512
#define HC   128          // H chunk size
#define NCH  (HH/HC)      // 8 chunks

typedef __attribute__((ext_vector_type(8)))  short short8;   // bf16x8 MFMA frag (4 VGPRs)
typedef __attribute__((ext_vector_type(16))) float f32x16;   // 32x32 MFMA accumulator

__device__ __forceinline__ unsigned short f2bf(float f) {
    // round-to-nearest-even f32 -> bf16
    unsigned int u = __float_as_uint(f);
    u = u + 0x7FFFu + ((u >> 16) & 1u);
    return (unsigned short)(u >> 16);
}

// Prep: emit weights in exact per-lane MFMA fragment order so that every
// weight load in the main loop is one contiguous 1 KiB wave burst.
//   w1f frag f = ((blk*16 + ks)*64 + lane), lane = g5*32 + l31:
//       elem j = W1[(ks*16 + g5*8 + j)][blk*32 + l31]      (32768 frags, 512 KiB)
//   w2f frag f = (((eblk*8 + hc)*8 + ks2)*64 + lane):
//       elem j = W2[(hc*128 + ks2*16 + g5*8 + j)][eblk*32 + l31]  (65536 frags, 1 MiB)
__global__ void prep_weights(const float* __restrict__ W1, const float* __restrict__ W2,
                             unsigned short* __restrict__ w1f, unsigned short* __restrict__ w2f) {
    int g = blockIdx.x * 512 + threadIdx.x;      // 192 blocks * 512 = 98304 exactly
    unsigned short tmp[8];
    if (g < 32768) {
        int f   = g;
        int l31 = f & 31;
        int g5  = (f >> 5) & 1;
        int ks  = (f >> 6) & 15;
        int blk = f >> 10;                        // 0..31
        int h   = blk * 32 + l31;
        int d0  = ks * 16 + g5 * 8;
        #pragma unroll
        for (int j = 0; j < 8; ++j) tmp[j] = f2bf(W1[(size_t)(d0 + j) * HH + h]);
        uint4 p;
        p.x = (unsigned int)tmp[0] | ((unsigned int)tmp[1] << 16);
        p.y = (unsigned int)tmp[2] | ((unsigned int)tmp[3] << 16);
        p.z = (unsigned int)tmp[4] | ((unsigned int)tmp[5] << 16);
        p.w = (unsigned int)tmp[6] | ((unsigned int)tmp[7] << 16);
        *(uint4*)(w1f + (size_t)f * 8) = p;
    } else {
        int f    = g - 32768;                     // 0..65535
        int l31  = f & 31;
        int g5   = (f >> 5) & 1;
        int ks2  = (f >> 6) & 7;
        int hc   = (f >> 9) & 7;
        int eblk = f >> 12;                       // 0..15
        int e    = eblk * 32 + l31;
        int h0   = hc * 128 + ks2 * 16 + g5 * 8;
        #pragma unroll
        for (int j = 0; j < 8; ++j) tmp[j] = f2bf(W2[(size_t)(h0 + j) * EE + e]);
        uint4 p;
        p.x = (unsigned int)tmp[0] | ((unsigned int)tmp[1] << 16);
        p.y = (unsigned int)tmp[2] | ((unsigned int)tmp[3] << 16);
        p.z = (unsigned int)tmp[4] | ((unsigned int)tmp[5] << 16);
        p.w = (unsigned int)tmp[6] | ((unsigned int)tmp[7] << 16);
        *(uint4*)(w2f + (size_t)f * 8) = p;
    }
}

// Fused: per-batch MLP + leave-one-out mean pooling + concat.
// grid = 2048 (one WG per batch), block = 512 (8 waves), 3 blocks/CU (48 KiB LDS).
__global__ __launch_bounds__(512, 6)
void fused_mlp_loo(const float* __restrict__ X,
                   const short8* __restrict__ w1f,   // fragment-ordered W1^T bf16
                   const short8* __restrict__ w2f,   // fragment-ordered W2^T bf16
                   const float* __restrict__ b1,
                   const float* __restrict__ b2,
                   float* __restrict__ out)
{
    // Xs: [64][256] bf16, row stride 512B, offset 0      (32 KiB, XOR-swizzled)
    // Hs: [64][128] bf16, row stride 256B, offset 32768  (16 KiB, single buffer)
    __shared__ __attribute__((aligned(16))) unsigned char lds[49152];

    const int bid = blockIdx.x;
    const int tid = threadIdx.x;
    const int w   = tid >> 6;    // wave 0..7
    const int l   = tid & 63;
    const int g5  = l >> 5;      // 0/1
    const int l31 = l & 31;
    const int wh  = w >> 1;      // GEMM1 hcol group 0..3
    const int wx  = w & 1;       // GEMM1 xrow group 0..1

    // ---- stage X (f32 -> bf16, XOR-swizzled) + copy inputs to out[..., 0:256] ----
    {
        const float4* Xv = (const float4*)(X + (size_t)bid * (NN * DD));
        #pragma unroll
        for (int k = 0; k < 8; ++k) {
            int f = tid + k * 512;           // float4 index in [0,4096)
            float4 v = Xv[f];                // fully coalesced
            int row = f >> 6;                // 0..63
            int c4  = f & 63;                // float4 within row
            uint2 p;
            p.x = (unsigned int)f2bf(v.x) | ((unsigned int)f2bf(v.y) << 16);
            p.y = (unsigned int)f2bf(v.z) | ((unsigned int)f2bf(v.w) << 16);
            int off = (c4 * 8) ^ ((row & 15) << 4);
            *(uint2*)(lds + row * 512 + off) = p;
            float4* ov = (float4*)(out + (size_t)(bid * NN + row) * (DD + EE));
            ov[c4] = v;                      // input copy (exact f32)
        }
    }
    __syncthreads();

    const int xrow = 32 * wx + l31;
    const unsigned char* xbase = lds + xrow * 512;
    const int xswz = (xrow & 15) << 4;

    f32x16 acc[2][2] = {};   // emb accumulators: wave owns rows 0..63 x cols [64w, 64w+64)

    // GEMM1 for chunk hc: c1 = h^T chunk (A = w1f frag, B = Xs frag)
    auto gemm1_compute = [&](int hc, f32x16& c1) {
        const short8* a1p = w1f + (size_t)((hc * 4 + wh) * 16) * 64 + l;
        #pragma unroll
        for (int ks = 0; ks < 16; ++ks) {
            short8 a1 = a1p[ks * 64];      // contiguous 1 KiB wave burst
            short8 xb = *(const short8*)(xbase + ((ks * 32 + 16 * g5) ^ xswz));
            c1 = __builtin_amdgcn_mfma_f32_32x32x16_bf16(a1, xb, c1, 0, 0, 0);
        }
    };

    // bias + relu + pack h chunk into Hs (b1 read direct from global: 4 KB,
    // L1-resident, broadcast across the 32-lane half-wave)
    auto pack_h = [&](int hc, const f32x16& c1) {
        unsigned char* hbase = lds + 32768 + xrow * 256;
        const int hswz = (xrow & 15) << 4;
        #pragma unroll
        for (int q = 0; q < 4; ++q) {
            float4 bb = *(const float4*)(b1 + hc * HC + 32 * wh + 4 * g5 + 8 * q);
            float v0 = fmaxf(c1[4 * q + 0] + bb.x, 0.f);
            float v1 = fmaxf(c1[4 * q + 1] + bb.y, 0.f);
            float v2 = fmaxf(c1[4 * q + 2] + bb.z, 0.f);
            float v3 = fmaxf(c1[4 * q + 3] + bb.w, 0.f);
            uint2 p;
            p.x = (unsigned int)f2bf(v0) | ((unsigned int)f2bf(v1) << 16);
            p.y = (unsigned int)f2bf(v2) | ((unsigned int)f2bf(v3) << 16);
            int off = (64 * wh + 16 * q + 8 * g5) ^ hswz;
            *(uint2*)(hbase + off) = p;
        }
    };

    // GEMM2 accumulate chunk hc: acc += Hs @ w2f[chunk,:]
    auto gemm2_step = [&](int hc) {
        const unsigned char* hrd = lds + 32768;
        const short8* b0p = w2f + (size_t)(((2 * w + 0) * 8 + hc) * 8) * 64 + l;
        const short8* b1p = w2f + (size_t)(((2 * w + 1) * 8 + hc) * 8) * 64 + l;
        #pragma unroll
        for (int ks2 = 0; ks2 < 8; ++ks2) {
            short8 a2[2];
            #pragma unroll
            for (int mf = 0; mf < 2; ++mf) {
                int row = 32 * mf + l31;
                a2[mf] = *(const short8*)(hrd + row * 256 +
                                          ((32 * ks2 + 16 * g5) ^ ((row & 15) << 4)));
            }
            short8 bw0 = b0p[ks2 * 64];    // contiguous 1 KiB wave bursts
            short8 bw1 = b1p[ks2 * 64];
            acc[0][0] = __builtin_amdgcn_mfma_f32_32x32x16_bf16(a2[0], bw0, acc[0][0], 0, 0, 0);
            acc[0][1] = __builtin_amdgcn_mfma_f32_32x32x16_bf16(a2[0], bw1, acc[0][1], 0, 0, 0);
            acc[1][0] = __builtin_amdgcn_mfma_f32_32x32x16_bf16(a2[1], bw0, acc[1][0], 0, 0, 0);
            acc[1][1] = __builtin_amdgcn_mfma_f32_32x32x16_bf16(a2[1], bw1, acc[1][1], 0, 0, 0);
        }
    };

    // ---- main loop: single Hs buffer, 2 barriers per chunk.
    // gemm1(i+1) weight loads sit before gemm2(i) so they overlap its MFMAs;
    // the short pack_h segment between barriers is hidden by the other
    // 2 co-resident blocks on the CU.
    {
        f32x16 c1 = {};
        gemm1_compute(0, c1);
        pack_h(0, c1);
    }
    __syncthreads();

    for (int i = 0; i < NCH - 1; ++i) {
        f32x16 c1 = {};
        gemm1_compute(i + 1, c1);   // w1 loads + Xs reads only, no Hs dependency
        gemm2_step(i);              // reads Hs(i)
        __syncthreads();            // all Hs(i) reads done
        pack_h(i + 1, c1);          // overwrite Hs with chunk i+1
        __syncthreads();            // Hs(i+1) visible
    }
    gemm2_step(NCH - 1);

    // ---- epilogue: in-register LOO. Wave owns all 64 rows of its 64 cols. ----
    float tsum[2];
    #pragma unroll
    for (int nf = 0; nf < 2; ++nf) {
        float s = 0.f;
        #pragma unroll
        for (int mf = 0; mf < 2; ++mf)
            #pragma unroll
            for (int r = 0; r < 16; ++r)
                s += acc[mf][nf][r];
        s += __shfl_xor(s, 32, 64);    // combine the two lane halves -> full 64-row column sum
        tsum[nf] = s;
    }
    const float b2c0 = b2[64 * w + l31];
    const float b2c1 = b2[64 * w + 32 + l31];
    const float inv63 = 1.0f / 63.0f;
    float* obase = out + (size_t)bid * NN * (DD + EE) + DD;
    #pragma unroll
    for (int mf = 0; mf < 2; ++mf) {
        #pragma unroll
        for (int r = 0; r < 16; ++r) {
            int row = 32 * mf + (r & 3) + 8 * (r >> 2) + 4 * g5;
            float* orow = obase + (size_t)row * (DD + EE);
            {
                float raw = acc[mf][0][r];
                orow[64 * w + l31] = (tsum[0] - raw) * inv63 + b2c0;
            }
            {
                float raw = acc[mf][1][r];
                orow[64 * w + 32 + l31] = (tsum[1] - raw) * inv63 + b2c1;
            }
        }
    }
}

extern "C" void kernel_launch(void* const* d_in, const int* in_sizes, int n_in,
                              void* d_out, int out_size, void* d_ws, size_t ws_size,
                              hipStream_t stream) {
    const float* X  = (const float*)d_in[0];
    const float* W1 = (const float*)d_in[1];
    const float* b1 = (const float*)d_in[2];
    const float* W2 = (const float*)d_in[3];
    const float* b2 = (const float*)d_in[4];
    float* out = (float*)d_out;

    unsigned short* w1f = (unsigned short*)d_ws;             // 32768 frags * 16B = 512 KiB
    unsigned short* w2f = w1f + (size_t)32768 * 8;           // 65536 frags * 16B = 1 MiB

    prep_weights<<<192, 512, 0, stream>>>(W1, W2, w1f, w2f);
    fused_mlp_loo<<<NB_B, 512, 0, stream>>>(X, (const short8*)w1f, (const short8*)w2f,
                                            b1, b2, out);
}

// Round 12
// 2743.044 us; speedup vs baseline: 1.0459x; 1.0459x over previous
//
#include <hip/hip_runtime.h>
#include <hip/hip_bf16.h>
#include <stdint.h>

// Problem constants
#define NB_B 2048
#define NN   64
#define DD   256
#define HH   1024
#define EE   512
#define HC   128          // H chunk size
#define NCH  (HH/HC)      // 8 chunks

typedef __attribute__((ext_vector_type(8)))  short short8;   // bf16x8 MFMA frag (4 VGPRs)
typedef __attribute__((ext_vector_type(16))) float f32x16;   // 32x32 MFMA accumulator

__device__ __forceinline__ unsigned short f2bf(float f) {
    // round-to-nearest-even f32 -> bf16
    unsigned int u = __float_as_uint(f);
    u = u + 0x7FFFu + ((u >> 16) & 1u);
    return (unsigned short)(u >> 16);
}

// Prep: emit weights in exact per-lane MFMA fragment order so that every
// weight load in the main loop is one contiguous 1 KiB wave burst.
//   w1f frag f = ((blk*16 + ks)*64 + lane), lane = g5*32 + l31:
//       elem j = W1[(ks*16 + g5*8 + j)][blk*32 + l31]      (32768 frags, 512 KiB)
//   w2f frag f = (((eblk*8 + hc)*8 + ks2)*64 + lane):
//       elem j = W2[(hc*128 + ks2*16 + g5*8 + j)][eblk*32 + l31]  (65536 frags, 1 MiB)
__global__ void prep_weights(const float* __restrict__ W1, const float* __restrict__ W2,
                             unsigned short* __restrict__ w1f, unsigned short* __restrict__ w2f) {
    int g = blockIdx.x * 512 + threadIdx.x;      // 192 blocks * 512 = 98304 exactly
    unsigned short tmp[8];
    if (g < 32768) {
        int f   = g;
        int l31 = f & 31;
        int g5  = (f >> 5) & 1;
        int ks  = (f >> 6) & 15;
        int blk = f >> 10;                        // 0..31
        int h   = blk * 32 + l31;
        int d0  = ks * 16 + g5 * 8;
        #pragma unroll
        for (int j = 0; j < 8; ++j) tmp[j] = f2bf(W1[(size_t)(d0 + j) * HH + h]);
        uint4 p;
        p.x = (unsigned int)tmp[0] | ((unsigned int)tmp[1] << 16);
        p.y = (unsigned int)tmp[2] | ((unsigned int)tmp[3] << 16);
        p.z = (unsigned int)tmp[4] | ((unsigned int)tmp[5] << 16);
        p.w = (unsigned int)tmp[6] | ((unsigned int)tmp[7] << 16);
        *(uint4*)(w1f + (size_t)f * 8) = p;
    } else {
        int f    = g - 32768;                     // 0..65535
        int l31  = f & 31;
        int g5   = (f >> 5) & 1;
        int ks2  = (f >> 6) & 7;
        int hc   = (f >> 9) & 7;
        int eblk = f >> 12;                       // 0..15
        int e    = eblk * 32 + l31;
        int h0   = hc * 128 + ks2 * 16 + g5 * 8;
        #pragma unroll
        for (int j = 0; j < 8; ++j) tmp[j] = f2bf(W2[(size_t)(h0 + j) * EE + e]);
        uint4 p;
        p.x = (unsigned int)tmp[0] | ((unsigned int)tmp[1] << 16);
        p.y = (unsigned int)tmp[2] | ((unsigned int)tmp[3] << 16);
        p.z = (unsigned int)tmp[4] | ((unsigned int)tmp[5] << 16);
        p.w = (unsigned int)tmp[6] | ((unsigned int)tmp[7] << 16);
        *(uint4*)(w2f + (size_t)f * 8) = p;
    }
}

// Fused: per-batch MLP + leave-one-out mean pooling + concat.
// grid = 2048 (one WG per batch), block = 512 (8 waves), 2 blocks/CU.
__global__ __launch_bounds__(512, 4)
void fused_mlp_loo(const float* __restrict__ X,
                   const short8* __restrict__ w1f,   // fragment-ordered W1^T bf16
                   const short8* __restrict__ w2f,   // fragment-ordered W2^T bf16
                   const float* __restrict__ b1,
                   const float* __restrict__ b2,
                   float* __restrict__ out)
{
    // Xs:   [64][256] bf16, row stride 512B, offset 0       (32 KiB, XOR-swizzled)
    // Hs[j]:[64][128] bf16, row stride 256B, offset 32768+j*16384  (2 x 16 KiB, double buffer)
    // Bs:   b1 copy, 1024 f32, offset 65536                 (4 KiB)
    __shared__ __attribute__((aligned(16))) unsigned char lds[69632];

    const int bid = blockIdx.x;
    const int tid = threadIdx.x;
    const int w   = tid >> 6;    // wave 0..7
    const int l   = tid & 63;
    const int g5  = l >> 5;      // 0/1
    const int l31 = l & 31;
    const int wh  = w >> 1;      // GEMM1 hcol group 0..3
    const int wx  = w & 1;       // GEMM1 xrow group 0..1

    // ---- stage b1 into LDS ----
    {
        float2 v = *(const float2*)(b1 + tid * 2);
        *(float2*)(lds + 65536 + tid * 8) = v;
    }
    // ---- stage X (f32 -> bf16, XOR-swizzled) + copy inputs to out[..., 0:256] ----
    {
        const float4* Xv = (const float4*)(X + (size_t)bid * (NN * DD));
        #pragma unroll
        for (int k = 0; k < 8; ++k) {
            int f = tid + k * 512;           // float4 index in [0,4096)
            float4 v = Xv[f];                // fully coalesced
            int row = f >> 6;                // 0..63
            int c4  = f & 63;                // float4 within row
            uint2 p;
            p.x = (unsigned int)f2bf(v.x) | ((unsigned int)f2bf(v.y) << 16);
            p.y = (unsigned int)f2bf(v.z) | ((unsigned int)f2bf(v.w) << 16);
            int off = (c4 * 8) ^ ((row & 15) << 4);
            *(uint2*)(lds + row * 512 + off) = p;
            float4* ov = (float4*)(out + (size_t)(bid * NN + row) * (DD + EE));
            ov[c4] = v;                      // input copy (exact f32)
        }
    }
    __syncthreads();

    const int xrow = 32 * wx + l31;
    const unsigned char* xbase = lds + xrow * 512;
    const int xswz = (xrow & 15) << 4;

    f32x16 acc[2][2] = {};   // emb accumulators: wave owns rows 0..63 x cols [64w, 64w+64)

    // GEMM1 for chunk hc with 4-way ILP: c1p[p] accumulates ks = p, p+4, p+8, p+12.
    // Breaks the 16-deep dependent MFMA chain into 4 independent chains of 4.
    auto gemm1_compute = [&](int hc, f32x16 (&c1p)[4]) {
        const short8* a1p = w1f + (size_t)((hc * 4 + wh) * 16) * 64 + l;
        #pragma unroll
        for (int kk = 0; kk < 4; ++kk) {
            #pragma unroll
            for (int p = 0; p < 4; ++p) {
                int ks = kk * 4 + p;
                short8 a1 = a1p[ks * 64];      // contiguous 1 KiB wave burst
                short8 xb = *(const short8*)(xbase + ((ks * 32 + 16 * g5) ^ xswz));
                c1p[p] = __builtin_amdgcn_mfma_f32_32x32x16_bf16(a1, xb, c1p[p], 0, 0, 0);
            }
        }
    };

    // bias + relu + pack h chunk into Hs[hc&1]; sums the 4 partial accumulators here.
    auto pack_h = [&](int hc, const f32x16 (&c1p)[4]) {
        unsigned char* hbase = lds + 32768 + (hc & 1) * 16384 + xrow * 256;
        const int hswz = (xrow & 15) << 4;
        const float* Bs = (const float*)(lds + 65536);
        #pragma unroll
        for (int q = 0; q < 4; ++q) {
            float4 bb = *(const float4*)(Bs + hc * HC + 32 * wh + 4 * g5 + 8 * q);
            float v0 = fmaxf((c1p[0][4*q+0] + c1p[1][4*q+0]) + (c1p[2][4*q+0] + c1p[3][4*q+0]) + bb.x, 0.f);
            float v1 = fmaxf((c1p[0][4*q+1] + c1p[1][4*q+1]) + (c1p[2][4*q+1] + c1p[3][4*q+1]) + bb.y, 0.f);
            float v2 = fmaxf((c1p[0][4*q+2] + c1p[1][4*q+2]) + (c1p[2][4*q+2] + c1p[3][4*q+2]) + bb.z, 0.f);
            float v3 = fmaxf((c1p[0][4*q+3] + c1p[1][4*q+3]) + (c1p[2][4*q+3] + c1p[3][4*q+3]) + bb.w, 0.f);
            uint2 p;
            p.x = (unsigned int)f2bf(v0) | ((unsigned int)f2bf(v1) << 16);
            p.y = (unsigned int)f2bf(v2) | ((unsigned int)f2bf(v3) << 16);
            int off = (64 * wh + 16 * q + 8 * g5) ^ hswz;
            *(uint2*)(hbase + off) = p;
        }
    };

    // GEMM2 accumulate chunk hc: acc += Hs[hc&1] @ w2f[chunk,:]
    auto gemm2_step = [&](int hc) {
        const unsigned char* hrd = lds + 32768 + (hc & 1) * 16384;
        const short8* b0p = w2f + (size_t)(((2 * w + 0) * 8 + hc) * 8) * 64 + l;
        const short8* b1p = w2f + (size_t)(((2 * w + 1) * 8 + hc) * 8) * 64 + l;
        #pragma unroll
        for (int ks2 = 0; ks2 < 8; ++ks2) {
            short8 a2[2];
            #pragma unroll
            for (int mf = 0; mf < 2; ++mf) {
                int row = 32 * mf + l31;
                a2[mf] = *(const short8*)(hrd + row * 256 +
                                          ((32 * ks2 + 16 * g5) ^ ((row & 15) << 4)));
            }
            short8 bw0 = b0p[ks2 * 64];    // contiguous 1 KiB wave bursts
            short8 bw1 = b1p[ks2 * 64];
            acc[0][0] = __builtin_amdgcn_mfma_f32_32x32x16_bf16(a2[0], bw0, acc[0][0], 0, 0, 0);
            acc[0][1] = __builtin_amdgcn_mfma_f32_32x32x16_bf16(a2[0], bw1, acc[0][1], 0, 0, 0);
            acc[1][0] = __builtin_amdgcn_mfma_f32_32x32x16_bf16(a2[1], bw0, acc[1][0], 0, 0, 0);
            acc[1][1] = __builtin_amdgcn_mfma_f32_32x32x16_bf16(a2[1], bw1, acc[1][1], 0, 0, 0);
        }
    };

    // ---- software-pipelined main loop: one barrier per chunk ----
    {
        f32x16 c1p[4] = {};
        gemm1_compute(0, c1p);
        pack_h(0, c1p);
    }
    __syncthreads();

    for (int i = 0; i < NCH - 1; ++i) {
        // produce chunk i+1 (long-latency weight loads) interleaved with consuming chunk i
        f32x16 c1p[4] = {};
        gemm1_compute(i + 1, c1p);
        gemm2_step(i);
        pack_h(i + 1, c1p);
        __syncthreads();
    }
    gemm2_step(NCH - 1);

    // ---- epilogue: in-register LOO. Wave owns all 64 rows of its 64 cols. ----
    float tsum[2];
    #pragma unroll
    for (int nf = 0; nf < 2; ++nf) {
        float s = 0.f;
        #pragma unroll
        for (int mf = 0; mf < 2; ++mf)
            #pragma unroll
            for (int r = 0; r < 16; ++r)
                s += acc[mf][nf][r];
        s += __shfl_xor(s, 32, 64);    // combine the two lane halves -> full 64-row column sum
        tsum[nf] = s;
    }
    const float b2c0 = b2[64 * w + l31];
    const float b2c1 = b2[64 * w + 32 + l31];
    const float inv63 = 1.0f / 63.0f;
    float* obase = out + (size_t)bid * NN * (DD + EE) + DD;
    #pragma unroll
    for (int mf = 0; mf < 2; ++mf) {
        #pragma unroll
        for (int r = 0; r < 16; ++r) {
            int row = 32 * mf + (r & 3) + 8 * (r >> 2) + 4 * g5;
            float* orow = obase + (size_t)row * (DD + EE);
            {
                float raw = acc[mf][0][r];
                orow[64 * w + l31] = (tsum[0] - raw) * inv63 + b2c0;
            }
            {
                float raw = acc[mf][1][r];
                orow[64 * w + 32 + l31] = (tsum[1] - raw) * inv63 + b2c1;
            }
        }
    }
}

extern "C" void kernel_launch(void* const* d_in, const int* in_sizes, int n_in,
                              void* d_out, int out_size, void* d_ws, size_t ws_size,
                              hipStream_t stream) {
    const float* X  = (const float*)d_in[0];
    const float* W1 = (const float*)d_in[1];
    const float* b1 = (const float*)d_in[2];
    const float* W2 = (const float*)d_in[3];
    const float* b2 = (const float*)d_in[4];
    float* out = (float*)d_out;

    unsigned short* w1f = (unsigned short*)d_ws;             // 32768 frags * 16B = 512 KiB
    unsigned short* w2f = w1f + (size_t)32768 * 8;           // 65536 frags * 16B = 1 MiB

    prep_weights<<<192, 512, 0, stream>>>(W1, W2, w1f, w2f);
    fused_mlp_loo<<<NB_B, 512, 0, stream>>>(X, (const short8*)w1f, (const short8*)w2f,
                                            b1, b2, out);
}

// Round 13
// 319.844 us; speedup vs baseline: 8.9699x; 8.5762x over previous
//
#include <hip/hip_runtime.h>
#include <hip/hip_bf16.h>
#include <stdint.h>

// Problem constants
#define NB_B 2048
#define NN   64
#define DD   256
#define HH   1024
#define EE   512
#define HC   128          // H chunk size
#define NCH  (HH/HC)      // 8 chunks

typedef __attribute__((ext_vector_type(8)))  short short8;   // bf16x8 MFMA frag (4 VGPRs)
typedef __attribute__((ext_vector_type(16))) float f32x16;   // 32x32 MFMA accumulator

__device__ __forceinline__ unsigned short f2bf(float f) {
    // round-to-nearest-even f32 -> bf16
    unsigned int u = __float_as_uint(f);
    u = u + 0x7FFFu + ((u >> 16) & 1u);
    return (unsigned short)(u >> 16);
}

// Prep: emit weights in exact per-lane MFMA fragment order so that every
// weight load in the main loop is one contiguous 1 KiB wave burst.
//   w1f frag f = ((blk*16 + ks)*64 + lane), lane = g5*32 + l31:
//       elem j = W1[(ks*16 + g5*8 + j)][blk*32 + l31]      (32768 frags, 512 KiB)
//   w2f frag f = (((eblk*8 + hc)*8 + ks2)*64 + lane):
//       elem j = W2[(hc*128 + ks2*16 + g5*8 + j)][eblk*32 + l31]  (65536 frags, 1 MiB)
__global__ void prep_weights(const float* __restrict__ W1, const float* __restrict__ W2,
                             unsigned short* __restrict__ w1f, unsigned short* __restrict__ w2f) {
    int g = blockIdx.x * 512 + threadIdx.x;      // 192 blocks * 512 = 98304 exactly
    unsigned short tmp[8];
    if (g < 32768) {
        int f   = g;
        int l31 = f & 31;
        int g5  = (f >> 5) & 1;
        int ks  = (f >> 6) & 15;
        int blk = f >> 10;                        // 0..31
        int h   = blk * 32 + l31;
        int d0  = ks * 16 + g5 * 8;
        #pragma unroll
        for (int j = 0; j < 8; ++j) tmp[j] = f2bf(W1[(size_t)(d0 + j) * HH + h]);
        uint4 p;
        p.x = (unsigned int)tmp[0] | ((unsigned int)tmp[1] << 16);
        p.y = (unsigned int)tmp[2] | ((unsigned int)tmp[3] << 16);
        p.z = (unsigned int)tmp[4] | ((unsigned int)tmp[5] << 16);
        p.w = (unsigned int)tmp[6] | ((unsigned int)tmp[7] << 16);
        *(uint4*)(w1f + (size_t)f * 8) = p;
    } else {
        int f    = g - 32768;                     // 0..65535
        int l31  = f & 31;
        int g5   = (f >> 5) & 1;
        int ks2  = (f >> 6) & 7;
        int hc   = (f >> 9) & 7;
        int eblk = f >> 12;                       // 0..15
        int e    = eblk * 32 + l31;
        int h0   = hc * 128 + ks2 * 16 + g5 * 8;
        #pragma unroll
        for (int j = 0; j < 8; ++j) tmp[j] = f2bf(W2[(size_t)(h0 + j) * EE + e]);
        uint4 p;
        p.x = (unsigned int)tmp[0] | ((unsigned int)tmp[1] << 16);
        p.y = (unsigned int)tmp[2] | ((unsigned int)tmp[3] << 16);
        p.z = (unsigned int)tmp[4] | ((unsigned int)tmp[5] << 16);
        p.w = (unsigned int)tmp[6] | ((unsigned int)tmp[7] << 16);
        *(uint4*)(w2f + (size_t)f * 8) = p;
    }
}

// Fused: per-batch MLP + leave-one-out mean pooling + concat.
// grid = 2048 (one WG per batch), block = 512 (8 waves), 2 blocks/CU.
__global__ __launch_bounds__(512, 4)
void fused_mlp_loo(const float* __restrict__ X,
                   const short8* __restrict__ w1f,   // fragment-ordered W1^T bf16
                   const short8* __restrict__ w2f,   // fragment-ordered W2^T bf16
                   const float* __restrict__ b1,
                   const float* __restrict__ b2,
                   float* __restrict__ out)
{
    // Xs:   [64][256] bf16, row stride 512B, offset 0       (32 KiB, XOR-swizzled)
    // Hs[j]:[64][128] bf16, row stride 256B, offset 32768+j*16384  (2 x 16 KiB, double buffer)
    // Bs:   b1 copy, 1024 f32, offset 65536                 (4 KiB)
    __shared__ __attribute__((aligned(16))) unsigned char lds[69632];

    const int bid = blockIdx.x;
    const int tid = threadIdx.x;
    const int w   = tid >> 6;    // wave 0..7
    const int l   = tid & 63;
    const int g5  = l >> 5;      // 0/1
    const int l31 = l & 31;
    const int wh  = w >> 1;      // GEMM1 hcol group 0..3
    const int wx  = w & 1;       // GEMM1 xrow group 0..1

    // ---- stage b1 into LDS ----
    {
        float2 v = *(const float2*)(b1 + tid * 2);
        *(float2*)(lds + 65536 + tid * 8) = v;
    }
    // ---- stage X (f32 -> bf16, XOR-swizzled) + copy inputs to out[..., 0:256] ----
    {
        const float4* Xv = (const float4*)(X + (size_t)bid * (NN * DD));
        #pragma unroll
        for (int k = 0; k < 8; ++k) {
            int f = tid + k * 512;           // float4 index in [0,4096)
            float4 v = Xv[f];                // fully coalesced
            int row = f >> 6;                // 0..63
            int c4  = f & 63;                // float4 within row
            uint2 p;
            p.x = (unsigned int)f2bf(v.x) | ((unsigned int)f2bf(v.y) << 16);
            p.y = (unsigned int)f2bf(v.z) | ((unsigned int)f2bf(v.w) << 16);
            int off = (c4 * 8) ^ ((row & 15) << 4);
            *(uint2*)(lds + row * 512 + off) = p;
            float4* ov = (float4*)(out + (size_t)(bid * NN + row) * (DD + EE));
            ov[c4] = v;                      // input copy (exact f32)
        }
    }
    __syncthreads();

    const int xrow = 32 * wx + l31;
    const unsigned char* xbase = lds + xrow * 512;
    const int xswz = (xrow & 15) << 4;

    f32x16 acc[2][2] = {};   // emb accumulators: wave owns rows 0..63 x cols [64w, 64w+64)

    // GEMM1 for chunk hc: c1 = h^T chunk (A = w1f frag, B = Xs frag)
    auto gemm1_compute = [&](int hc, f32x16& c1) {
        const short8* a1p = w1f + (size_t)((hc * 4 + wh) * 16) * 64 + l;
        #pragma unroll
        for (int ks = 0; ks < 16; ++ks) {
            short8 a1 = a1p[ks * 64];      // contiguous 1 KiB wave burst
            short8 xb = *(const short8*)(xbase + ((ks * 32 + 16 * g5) ^ xswz));
            c1 = __builtin_amdgcn_mfma_f32_32x32x16_bf16(a1, xb, c1, 0, 0, 0);
        }
    };

    // bias + relu + pack h chunk into Hs[hc&1]
    auto pack_h = [&](int hc, const f32x16& c1) {
        unsigned char* hbase = lds + 32768 + (hc & 1) * 16384 + xrow * 256;
        const int hswz = (xrow & 15) << 4;
        const float* Bs = (const float*)(lds + 65536);
        #pragma unroll
        for (int q = 0; q < 4; ++q) {
            float4 bb = *(const float4*)(Bs + hc * HC + 32 * wh + 4 * g5 + 8 * q);
            float v0 = fmaxf(c1[4 * q + 0] + bb.x, 0.f);
            float v1 = fmaxf(c1[4 * q + 1] + bb.y, 0.f);
            float v2 = fmaxf(c1[4 * q + 2] + bb.z, 0.f);
            float v3 = fmaxf(c1[4 * q + 3] + bb.w, 0.f);
            uint2 p;
            p.x = (unsigned int)f2bf(v0) | ((unsigned int)f2bf(v1) << 16);
            p.y = (unsigned int)f2bf(v2) | ((unsigned int)f2bf(v3) << 16);
            int off = (64 * wh + 16 * q + 8 * g5) ^ hswz;
            *(uint2*)(hbase + off) = p;
        }
    };

    // GEMM2 accumulate chunk hc: acc += Hs[hc&1] @ w2f[chunk,:]
    auto gemm2_step = [&](int hc) {
        const unsigned char* hrd = lds + 32768 + (hc & 1) * 16384;
        const short8* b0p = w2f + (size_t)(((2 * w + 0) * 8 + hc) * 8) * 64 + l;
        const short8* b1p = w2f + (size_t)(((2 * w + 1) * 8 + hc) * 8) * 64 + l;
        #pragma unroll
        for (int ks2 = 0; ks2 < 8; ++ks2) {
            short8 a2[2];
            #pragma unroll
            for (int mf = 0; mf < 2; ++mf) {
                int row = 32 * mf + l31;
                a2[mf] = *(const short8*)(hrd + row * 256 +
                                          ((32 * ks2 + 16 * g5) ^ ((row & 15) << 4)));
            }
            short8 bw0 = b0p[ks2 * 64];    // contiguous 1 KiB wave bursts
            short8 bw1 = b1p[ks2 * 64];
            acc[0][0] = __builtin_amdgcn_mfma_f32_32x32x16_bf16(a2[0], bw0, acc[0][0], 0, 0, 0);
            acc[0][1] = __builtin_amdgcn_mfma_f32_32x32x16_bf16(a2[0], bw1, acc[0][1], 0, 0, 0);
            acc[1][0] = __builtin_amdgcn_mfma_f32_32x32x16_bf16(a2[1], bw0, acc[1][0], 0, 0, 0);
            acc[1][1] = __builtin_amdgcn_mfma_f32_32x32x16_bf16(a2[1], bw1, acc[1][1], 0, 0, 0);
        }
    };

    // ---- software-pipelined main loop: one barrier per chunk ----
    {
        f32x16 c1 = {};
        gemm1_compute(0, c1);
        pack_h(0, c1);
    }
    __syncthreads();

    for (int i = 0; i < NCH - 1; ++i) {
        // produce chunk i+1 (long-latency weight loads) interleaved with consuming chunk i
        f32x16 c1 = {};
        gemm1_compute(i + 1, c1);
        gemm2_step(i);
        pack_h(i + 1, c1);
        __syncthreads();
    }
    gemm2_step(NCH - 1);

    // ---- epilogue: in-register LOO. Wave owns all 64 rows of its 64 cols. ----
    float tsum[2];
    #pragma unroll
    for (int nf = 0; nf < 2; ++nf) {
        float s = 0.f;
        #pragma unroll
        for (int mf = 0; mf < 2; ++mf)
            #pragma unroll
            for (int r = 0; r < 16; ++r)
                s += acc[mf][nf][r];
        s += __shfl_xor(s, 32, 64);    // combine the two lane halves -> full 64-row column sum
        tsum[nf] = s;
    }
    const float b2c0 = b2[64 * w + l31];
    const float b2c1 = b2[64 * w + 32 + l31];
    const float inv63 = 1.0f / 63.0f;
    float* obase = out + (size_t)bid * NN * (DD + EE) + DD;
    #pragma unroll
    for (int mf = 0; mf < 2; ++mf) {
        #pragma unroll
        for (int r = 0; r < 16; ++r) {
            int row = 32 * mf + (r & 3) + 8 * (r >> 2) + 4 * g5;
            float* orow = obase + (size_t)row * (DD + EE);
            {
                float raw = acc[mf][0][r];
                orow[64 * w + l31] = (tsum[0] - raw) * inv63 + b2c0;
            }
            {
                float raw = acc[mf][1][r];
                orow[64 * w + 32 + l31] = (tsum[1] - raw) * inv63 + b2c1;
            }
        }
    }
}

extern "C" void kernel_launch(void* const* d_in, const int* in_sizes, int n_in,
                              void* d_out, int out_size, void* d_ws, size_t ws_size,
                              hipStream_t stream) {
    const float* X  = (const float*)d_in[0];
    const float* W1 = (const float*)d_in[1];
    const float* b1 = (const float*)d_in[2];
    const float* W2 = (const float*)d_in[3];
    const float* b2 = (const float*)d_in[4];
    float* out = (float*)d_out;

    unsigned short* w1f = (unsigned short*)d_ws;             // 32768 frags * 16B = 512 KiB
    unsigned short* w2f = w1f + (size_t)32768 * 8;           // 65536 frags * 16B = 1 MiB

    prep_weights<<<192, 512, 0, stream>>>(W1, W2, w1f, w2f);
    fused_mlp_loo<<<NB_B, 512, 0, stream>>>(X, (const short8*)w1f, (const short8*)w2f,
                                            b1, b2, out);
}